// Round 1
// baseline (4164.510 us; speedup 1.0000x reference)
//
#include <hip/hip_runtime.h>

// Problem constants
#define B_ 4
#define T_ 8192
#define C_ 1024
#define H_ 8
#define D_ 128
#define M_ (B_*T_)   // 32768 rows

// ---------------------------------------------------------------- wave utils
__device__ __forceinline__ float wave_sum(float v) {
#pragma unroll
  for (int off = 32; off > 0; off >>= 1) v += __shfl_xor(v, off, 64);
  return v;
}
__device__ __forceinline__ float wave_max(float v) {
#pragma unroll
  for (int off = 32; off > 0; off >>= 1) v = fmaxf(v, __shfl_xor(v, off, 64));
  return v;
}

// ---------------------------------------------------------------- GEMM + bias
// out[M,N] = A[M,K] @ W[K,N] + bias[N]; row-major; M%128==0, N%128==0, K%16==0
// 128x128 tile, BK=16, 256 threads, 8x8 acc per thread.
__global__ __launch_bounds__(256) void gemm_bias(
    const float* __restrict__ A, const float* __restrict__ W,
    const float* __restrict__ bias, float* __restrict__ out,
    int M, int N, int K)
{
  __shared__ float As[16][132];   // stride 132: padded, 16B-aligned rows
  __shared__ float Bs[16][132];
  const int tid  = threadIdx.x;
  const int bm   = blockIdx.y * 128;
  const int bn   = blockIdx.x * 128;
  const int arow = tid >> 2;          // 0..63
  const int acol = (tid & 3) << 2;    // 0,4,8,12
  const int brow = tid >> 5;          // 0..7
  const int bcol = (tid & 31) << 2;   // 0..124
  const int tx   = tid & 15, ty = tid >> 4;
  float acc[8][8] = {};

  const float* Aptr  = A + (size_t)(bm + arow) * K + acol;
  const float* Aptr2 = Aptr + (size_t)64 * K;
  const float* Wptr  = W + (size_t)brow * N + bn + bcol;
  const float* Wptr2 = Wptr + (size_t)8 * N;

  for (int k0 = 0; k0 < K; k0 += 16) {
    float4 a0 = *(const float4*)(Aptr  + k0);
    float4 a1 = *(const float4*)(Aptr2 + k0);
    float4 b0 = *(const float4*)(Wptr  + (size_t)k0 * N);
    float4 b1 = *(const float4*)(Wptr2 + (size_t)k0 * N);
    __syncthreads();
    As[acol+0][arow]    = a0.x; As[acol+1][arow]    = a0.y;
    As[acol+2][arow]    = a0.z; As[acol+3][arow]    = a0.w;
    As[acol+0][arow+64] = a1.x; As[acol+1][arow+64] = a1.y;
    As[acol+2][arow+64] = a1.z; As[acol+3][arow+64] = a1.w;
    *(float4*)&Bs[brow  ][bcol] = b0;
    *(float4*)&Bs[brow+8][bcol] = b1;
    __syncthreads();
#pragma unroll
    for (int kk = 0; kk < 16; ++kk) {
      float a[8], b[8];
      *(float4*)&a[0] = *(const float4*)&As[kk][ty*8];
      *(float4*)&a[4] = *(const float4*)&As[kk][ty*8+4];
      *(float4*)&b[0] = *(const float4*)&Bs[kk][tx*8];
      *(float4*)&b[4] = *(const float4*)&Bs[kk][tx*8+4];
#pragma unroll
      for (int i = 0; i < 8; ++i)
#pragma unroll
        for (int j = 0; j < 8; ++j)
          acc[i][j] = fmaf(a[i], b[j], acc[i][j]);
    }
  }

  float4 bv0 = *(const float4*)&bias[bn + tx*8];
  float4 bv1 = *(const float4*)&bias[bn + tx*8 + 4];
#pragma unroll
  for (int i = 0; i < 8; ++i) {
    size_t ro = (size_t)(bm + ty*8 + i) * N + bn + tx*8;
    float4 o0 = make_float4(acc[i][0]+bv0.x, acc[i][1]+bv0.y,
                            acc[i][2]+bv0.z, acc[i][3]+bv0.w);
    float4 o1 = make_float4(acc[i][4]+bv1.x, acc[i][5]+bv1.y,
                            acc[i][6]+bv1.z, acc[i][7]+bv1.w);
    *(float4*)&out[ro]   = o0;
    *(float4*)&out[ro+4] = o1;
  }
}

// ---------------------------------------------------------------- softmax over D=128
// In-place softmax over each 128-wide head segment. One wave per (row, head).
// If ksum != nullptr (the q pass): also computes dinv[bh*T + t] = 1/(q . ksum[bh]).
__global__ __launch_bounds__(256) void softmax_head(
    float* __restrict__ buf, const float* __restrict__ ksum, float* __restrict__ dinv)
{
  const int wave = threadIdx.x >> 6, lane = threadIdx.x & 63;
  const size_t rh  = (size_t)blockIdx.x * 4 + wave;   // rh = m*H + h, over M_*H_
  const size_t off = rh * 128 + (size_t)lane * 2;
  float2 v = *(float2*)&buf[off];
  float mx = wave_max(fmaxf(v.x, v.y));
  float ex = expf(v.x - mx), ey = expf(v.y - mx);
  float inv = 1.0f / wave_sum(ex + ey);
  ex *= inv; ey *= inv;
  *(float2*)&buf[off] = make_float2(ex, ey);
  if (ksum) {
    const int m = (int)(rh >> 3), h = (int)(rh & 7);
    const int b = m >> 13, t = m & 8191;
    const int bh = b * 8 + h;
    const float* ks = ksum + (size_t)bh * 128 + lane * 2;
    float dot = wave_sum(ex * ks[0] + ey * ks[1]);
    if (lane == 0) dinv[(size_t)bh * T_ + t] = 1.0f / dot;
  }
}

// ---------------------------------------------------------------- ksum[bh][d] = sum_t k[b,t,h,d]
__global__ __launch_bounds__(256) void ksum_kernel(
    const float* __restrict__ k, float* __restrict__ ksum)
{
  const int bh = blockIdx.x; const int b = bh >> 3, h = bh & 7;
  const int tc = blockIdx.y;                // 16 chunks x 512 t
  const int d    = threadIdx.x & 127;
  const int half = threadIdx.x >> 7;        // 0/1
  const float* base = k + ((size_t)b*T_ + tc*512 + half) * C_ + h*D_ + d;
  float s = 0.f;
  for (int t = 0; t < 512; t += 2) s += base[(size_t)t * C_];
  __shared__ float sm[256];
  sm[threadIdx.x] = s;
  __syncthreads();
  if (threadIdx.x < 128)
    atomicAdd(&ksum[(size_t)bh*128 + threadIdx.x], sm[threadIdx.x] + sm[threadIdx.x + 128]);
}

// ---------------------------------------------------------------- ctx[bh][d][e] = sum_t k[t,d]*v[t,e]
// One block = full 128x128 output for a 256-long t-chunk; fp32 atomicAdd reduce.
__global__ __launch_bounds__(256) void ctx_kernel(
    const float* __restrict__ k, const float* __restrict__ v, float* __restrict__ ctx)
{
  const int bh = blockIdx.x; const int b = bh >> 3, h = bh & 7;
  const int t0 = blockIdx.y * 256;          // 32 chunks x 256 t
  const int tid  = threadIdx.x;
  const int lrow = tid >> 5;                // 0..7 (t within 16-tile)
  const int lcol = (tid & 31) << 2;         // 0..124
  const int tx   = tid & 15, ty = tid >> 4;
  __shared__ float Ks[16][132];
  __shared__ float Vs[16][132];
  float acc[8][8] = {};
  const size_t rbase = ((size_t)b*T_ + t0) * C_ + (size_t)h * D_;

  for (int kt = 0; kt < 256; kt += 16) {
    const size_t r0 = rbase + (size_t)(kt + lrow) * C_ + lcol;
    const size_t r1 = r0 + (size_t)8 * C_;
    float4 k0 = *(const float4*)&k[r0];
    float4 k1 = *(const float4*)&k[r1];
    float4 v0 = *(const float4*)&v[r0];
    float4 v1 = *(const float4*)&v[r1];
    __syncthreads();
    *(float4*)&Ks[lrow  ][lcol] = k0;
    *(float4*)&Ks[lrow+8][lcol] = k1;
    *(float4*)&Vs[lrow  ][lcol] = v0;
    *(float4*)&Vs[lrow+8][lcol] = v1;
    __syncthreads();
#pragma unroll
    for (int kk = 0; kk < 16; ++kk) {
      float a[8], bb[8];
      *(float4*)&a[0]  = *(const float4*)&Ks[kk][ty*8];
      *(float4*)&a[4]  = *(const float4*)&Ks[kk][ty*8+4];
      *(float4*)&bb[0] = *(const float4*)&Vs[kk][tx*8];
      *(float4*)&bb[4] = *(const float4*)&Vs[kk][tx*8+4];
#pragma unroll
      for (int i = 0; i < 8; ++i)
#pragma unroll
        for (int j = 0; j < 8; ++j)
          acc[i][j] = fmaf(a[i], bb[j], acc[i][j]);
    }
  }
  float* cb = ctx + (size_t)bh * (D_*D_);
#pragma unroll
  for (int i = 0; i < 8; ++i)
#pragma unroll
    for (int j = 0; j < 8; ++j)
      atomicAdd(&cb[(size_t)(ty*8+i)*D_ + tx*8 + j], acc[i][j]);
}

// ---------------------------------------------------------------- y = (q @ ctx) * Dinv + q
// Per (bh): [128-row t-tile] x [128x128 ctx], K = D = 128. Same skeleton as gemm_bias.
__global__ __launch_bounds__(256) void y_gemm(
    const float* __restrict__ q, const float* __restrict__ ctx,
    const float* __restrict__ dinv, float* __restrict__ y)
{
  const int bh = blockIdx.y; const int b = bh >> 3, h = bh & 7;
  const int t0 = blockIdx.x * 128;
  const int tid  = threadIdx.x;
  const int arow = tid >> 2, acol = (tid & 3) << 2;
  const int brow = tid >> 5, bcol = (tid & 31) << 2;
  const int tx   = tid & 15, ty = tid >> 4;
  __shared__ float As[16][132];
  __shared__ float Bs[16][132];
  float acc[8][8] = {};
  const size_t qbase = ((size_t)b*T_ + t0) * C_ + (size_t)h * D_;
  const float* cbase = ctx + (size_t)bh * (D_*D_);

  for (int k0 = 0; k0 < 128; k0 += 16) {
    float4 a0 = *(const float4*)&q[qbase + (size_t)arow      * C_ + k0 + acol];
    float4 a1 = *(const float4*)&q[qbase + (size_t)(arow+64) * C_ + k0 + acol];
    float4 b0 = *(const float4*)&cbase[(size_t)(k0+brow  )*D_ + bcol];
    float4 b1 = *(const float4*)&cbase[(size_t)(k0+brow+8)*D_ + bcol];
    __syncthreads();
    As[acol+0][arow]    = a0.x; As[acol+1][arow]    = a0.y;
    As[acol+2][arow]    = a0.z; As[acol+3][arow]    = a0.w;
    As[acol+0][arow+64] = a1.x; As[acol+1][arow+64] = a1.y;
    As[acol+2][arow+64] = a1.z; As[acol+3][arow+64] = a1.w;
    *(float4*)&Bs[brow  ][bcol] = b0;
    *(float4*)&Bs[brow+8][bcol] = b1;
    __syncthreads();
#pragma unroll
    for (int kk = 0; kk < 16; ++kk) {
      float a[8], bb[8];
      *(float4*)&a[0]  = *(const float4*)&As[kk][ty*8];
      *(float4*)&a[4]  = *(const float4*)&As[kk][ty*8+4];
      *(float4*)&bb[0] = *(const float4*)&Bs[kk][tx*8];
      *(float4*)&bb[4] = *(const float4*)&Bs[kk][tx*8+4];
#pragma unroll
      for (int i = 0; i < 8; ++i)
#pragma unroll
        for (int j = 0; j < 8; ++j)
          acc[i][j] = fmaf(a[i], bb[j], acc[i][j]);
    }
  }

  const float* dv = dinv + (size_t)bh * T_ + t0;
#pragma unroll
  for (int i = 0; i < 8; ++i) {
    const int t = ty*8 + i;
    const float di = dv[t];
    const size_t ro = qbase + (size_t)t * C_ + tx*8;
    float4 q0 = *(const float4*)&q[ro];
    float4 q1 = *(const float4*)&q[ro+4];
    float4 o0 = make_float4(fmaf(acc[i][0], di, q0.x), fmaf(acc[i][1], di, q0.y),
                            fmaf(acc[i][2], di, q0.z), fmaf(acc[i][3], di, q0.w));
    float4 o1 = make_float4(fmaf(acc[i][4], di, q1.x), fmaf(acc[i][5], di, q1.y),
                            fmaf(acc[i][6], di, q1.z), fmaf(acc[i][7], di, q1.w));
    *(float4*)&y[ro]   = o0;
    *(float4*)&y[ro+4] = o1;
  }
}

// ---------------------------------------------------------------- launch
extern "C" void kernel_launch(void* const* d_in, const int* in_sizes, int n_in,
                              void* d_out, int out_size, void* d_ws, size_t ws_size,
                              hipStream_t stream)
{
  const float* x  = (const float*)d_in[0];
  const float* Wq = (const float*)d_in[1];
  const float* bq = (const float*)d_in[2];
  const float* Wk = (const float*)d_in[3];
  const float* bk = (const float*)d_in[4];
  const float* Wv = (const float*)d_in[5];
  const float* bv = (const float*)d_in[6];
  const float* Wp = (const float*)d_in[7];
  const float* bp = (const float*)d_in[8];
  float* out = (float*)d_out;

  // workspace layout (fp32): q | k | v | ctx | ksum | dinv   (~387 MB)
  float* q    = (float*)d_ws;
  float* k    = q    + (size_t)M_ * C_;
  float* v    = k    + (size_t)M_ * C_;
  float* ctx  = v    + (size_t)M_ * C_;
  float* ksum = ctx  + (size_t)B_ * H_ * D_ * D_;
  float* dinv = ksum + (size_t)B_ * H_ * D_;
  float* y    = k;   // k/v dead after ctx_kernel; reuse k for y

  // zero the atomic accumulators (ws is poisoned 0xAA before every launch)
  hipMemsetAsync(ctx, 0, ((size_t)B_*H_*D_*D_ + (size_t)B_*H_*D_) * sizeof(float), stream);

  dim3 blk(256);
  dim3 gproj(C_/128, M_/128);                 // 8 x 256 blocks

  gemm_bias<<<gproj, blk, 0, stream>>>(x, Wq, bq, q, M_, C_, C_);
  gemm_bias<<<gproj, blk, 0, stream>>>(x, Wk, bk, k, M_, C_, C_);
  gemm_bias<<<gproj, blk, 0, stream>>>(x, Wv, bv, v, M_, C_, C_);

  softmax_head<<<dim3(M_*H_/4), blk, 0, stream>>>(k, nullptr, nullptr);
  ksum_kernel <<<dim3(B_*H_, 16), blk, 0, stream>>>(k, ksum);
  softmax_head<<<dim3(M_*H_/4), blk, 0, stream>>>(q, ksum, dinv);
  ctx_kernel  <<<dim3(B_*H_, 32), blk, 0, stream>>>(k, v, ctx);
  y_gemm      <<<dim3(T_/128, B_*H_), blk, 0, stream>>>(q, ctx, dinv, y);

  gemm_bias<<<gproj, blk, 0, stream>>>(y, Wp, bp, out, M_, C_, C_);
}

// Round 2
// 1427.256 us; speedup vs baseline: 2.9178x; 2.9178x over previous
//
#include <hip/hip_runtime.h>

// Problem constants
#define B_ 4
#define T_ 8192
#define C_ 1024
#define H_ 8
#define D_ 128
#define M_ (B_*T_)   // 32768 rows

typedef __attribute__((ext_vector_type(8))) short bf16x8;   // 8 bf16 = 4 VGPRs
typedef __attribute__((ext_vector_type(4))) float f32x4;

// ---------------------------------------------------------------- bf16 helpers
__device__ __forceinline__ unsigned short f2b(float f) {   // RNE f32->bf16
  union { float f; unsigned int u; } x; x.f = f;
  unsigned int r = x.u + 0x7fffu + ((x.u >> 16) & 1u);
  return (unsigned short)(r >> 16);
}
__device__ __forceinline__ float b2f(unsigned short u) {
  union { float f; unsigned int u; } x; x.u = ((unsigned int)u) << 16; return x.f;
}

// async global->LDS, 16B per lane. LDS dest is wave-uniform base + lane*16.
__device__ __forceinline__ void gl2lds16(const void* g, void* l) {
  __builtin_amdgcn_global_load_lds((const __attribute__((address_space(1))) void*)g,
                                   (__attribute__((address_space(3))) void*)l, 16, 0, 0);
}

// ---------------------------------------------------------------- wave utils
__device__ __forceinline__ float wave_sum(float v) {
#pragma unroll
  for (int off = 32; off > 0; off >>= 1) v += __shfl_xor(v, off, 64);
  return v;
}
__device__ __forceinline__ float wave_max(float v) {
#pragma unroll
  for (int off = 32; off > 0; off >>= 1) v = fmaxf(v, __shfl_xor(v, off, 64));
  return v;
}

// ---------------------------------------------------------------- MFMA GEMM + bias
// out[M,N] = A[M,K](bf16) @ Bt[N,K]^T(bf16) + bias[N]
// 128x128 tile, BK=64, 256 threads = 4 waves in 2x2, each wave 64x64 (4x4 MFMA tiles).
// LDS tiles 128 rows x 64 bf16 (128 B/row), 16B-chunk XOR swizzle: LDS(row,c)
// holds logical k-chunk c ^ (row&7)  -> conflict-free ds_read_b128 frag loads
// while keeping the linear lane-order layout global_load_lds requires.
template<typename OutT>
__global__ __launch_bounds__(256) void mfma_gemm_bias(
    const unsigned short* __restrict__ A,   // [M][K] bf16
    const unsigned short* __restrict__ Bt,  // [N][K] bf16
    const float* __restrict__ bias,         // [N]
    OutT* __restrict__ out,                 // [M][N]
    int M, int N, int K)
{
  __shared__ __align__(16) char lds[32768];
  char* As = lds;
  char* Bs = lds + 16384;
  const int tid  = threadIdx.x;
  const int w    = tid >> 6, lane = tid & 63;
  const int bm   = blockIdx.y * 128, bn = blockIdx.x * 128;
  const int wrow = (w >> 1) * 64, wcol = (w & 1) * 64;
  const int l15  = lane & 15, l4 = lane >> 4;

  f32x4 acc[4][4] = {};

  // staging geometry: chunk ch = w*4+j (1 KB each); lane covers row ch*8+(lane>>3),
  // stored 16B-chunk c = lane&7; fetches logical k-chunk kc = c ^ (row&7).
  const int srow = lane >> 3;
  const int sc   = lane & 7;

  for (int k0 = 0; k0 < K; k0 += 64) {
    __syncthreads();   // previous iter's frag reads done before overwrite
#pragma unroll
    for (int j = 0; j < 4; ++j) {
      const int ch  = w * 4 + j;
      const int row = ch * 8 + srow;
      const int kc  = sc ^ (row & 7);
      const char* ga = (const char*)(A  + (size_t)(bm + row) * K + k0) + kc * 16;
      const char* gb = (const char*)(Bt + (size_t)(bn + row) * K + k0) + kc * 16;
      gl2lds16(ga, As + ch * 1024 + lane * 16);
      gl2lds16(gb, Bs + ch * 1024 + lane * 16);
    }
    __syncthreads();   // compiler drains vmcnt before s_barrier

#pragma unroll
    for (int ks = 0; ks < 2; ++ks) {
      bf16x8 af[4], bf[4];
#pragma unroll
      for (int i = 0; i < 4; ++i) {
        const int m  = wrow + i * 16 + l15;       // frag row (A) / row (B)
        const int n  = wcol + i * 16 + l15;
        const int kc = ks * 4 + l4;               // logical 16B k-chunk
        af[i] = *(const bf16x8*)(As + m * 128 + ((kc ^ (m & 7)) * 16));
        bf[i] = *(const bf16x8*)(Bs + n * 128 + ((kc ^ (n & 7)) * 16));
      }
#pragma unroll
      for (int i = 0; i < 4; ++i)
#pragma unroll
        for (int j = 0; j < 4; ++j)
          acc[i][j] = __builtin_amdgcn_mfma_f32_16x16x32_bf16(af[i], bf[j], acc[i][j], 0, 0, 0);
    }
  }

  // epilogue: C/D layout col = lane&15, row = (lane>>4)*4 + reg
#pragma unroll
  for (int j = 0; j < 4; ++j) {
    const int col = bn + wcol + j * 16 + l15;
    const float bv = bias[col];
#pragma unroll
    for (int i = 0; i < 4; ++i) {
      const int rbase = bm + wrow + i * 16 + l4 * 4;
#pragma unroll
      for (int r = 0; r < 4; ++r) {
        const float val = acc[i][j][r] + bv;
        if constexpr (sizeof(OutT) == 4)
          out[(size_t)(rbase + r) * N + col] = val;
        else
          ((unsigned short*)out)[(size_t)(rbase + r) * N + col] = f2b(val);
      }
    }
  }
}

// ---------------------------------------------------------------- conversions
// fp32 -> bf16, n must be divisible by 2048 (grid sized exactly)
__global__ __launch_bounds__(256) void conv_bf16(
    const float* __restrict__ in, unsigned short* __restrict__ out)
{
  const size_t i = ((size_t)blockIdx.x * 256 + threadIdx.x) * 8;
  float4 a = *(const float4*)(in + i);
  float4 b = *(const float4*)(in + i + 4);
  union { unsigned short s[8]; uint4 v; } pk;
  pk.s[0] = f2b(a.x); pk.s[1] = f2b(a.y); pk.s[2] = f2b(a.z); pk.s[3] = f2b(a.w);
  pk.s[4] = f2b(b.x); pk.s[5] = f2b(b.y); pk.s[6] = f2b(b.z); pk.s[7] = f2b(b.w);
  *(uint4*)(out + i) = pk.v;
}

// W[K=1024][N=1024] fp32 -> Wt[N][K] bf16 (transpose + cast), 32x32 LDS tiles
__global__ __launch_bounds__(256) void convT_w(
    const float* __restrict__ W, unsigned short* __restrict__ Wt)
{
  __shared__ float s[32][33];
  const int k0 = blockIdx.x * 32, n0 = blockIdx.y * 32;
  const int tx = threadIdx.x & 31, ty = threadIdx.x >> 5;   // 32 x 8
#pragma unroll
  for (int r = ty; r < 32; r += 8) s[r][tx] = W[(size_t)(k0 + r) * 1024 + n0 + tx];
  __syncthreads();
#pragma unroll
  for (int r = ty; r < 32; r += 8) Wt[(size_t)(n0 + r) * 1024 + k0 + tx] = f2b(s[tx][r]);
}

// ---------------------------------------------------------------- softmax over D=128
// In-place softmax over each 128-wide head segment (fp32). One wave per (row, head).
// If ksum != nullptr (q pass): also dinv[bh*T + t] = 1/(q . ksum[bh]).
__global__ __launch_bounds__(256) void softmax_head(
    float* __restrict__ buf, const float* __restrict__ ksum, float* __restrict__ dinv)
{
  const int wave = threadIdx.x >> 6, lane = threadIdx.x & 63;
  const size_t rh  = (size_t)blockIdx.x * 4 + wave;   // rh = m*H + h
  const size_t off = rh * 128 + (size_t)lane * 2;
  float2 v = *(float2*)&buf[off];
  float mx = wave_max(fmaxf(v.x, v.y));
  float ex = expf(v.x - mx), ey = expf(v.y - mx);
  float inv = 1.0f / wave_sum(ex + ey);
  ex *= inv; ey *= inv;
  *(float2*)&buf[off] = make_float2(ex, ey);
  if (ksum) {
    const int m = (int)(rh >> 3), h = (int)(rh & 7);
    const int b = m >> 13, t = m & 8191;
    const int bh = b * 8 + h;
    const float* ks = ksum + (size_t)bh * 128 + lane * 2;
    float dot = wave_sum(ex * ks[0] + ey * ks[1]);
    if (lane == 0) dinv[(size_t)bh * T_ + t] = 1.0f / dot;
  }
}

// ---------------------------------------------------------------- ksum[bh][d] = sum_t k
__global__ __launch_bounds__(256) void ksum_kernel(
    const float* __restrict__ k, float* __restrict__ ksum)
{
  const int bh = blockIdx.x; const int b = bh >> 3, h = bh & 7;
  const int tc = blockIdx.y;
  const int d    = threadIdx.x & 127;
  const int half = threadIdx.x >> 7;
  const float* base = k + ((size_t)b*T_ + tc*512 + half) * C_ + h*D_ + d;
  float s = 0.f;
  for (int t = 0; t < 512; t += 2) s += base[(size_t)t * C_];
  __shared__ float sm[256];
  sm[threadIdx.x] = s;
  __syncthreads();
  if (threadIdx.x < 128)
    atomicAdd(&ksum[(size_t)bh*128 + threadIdx.x], sm[threadIdx.x] + sm[threadIdx.x + 128]);
}

// ---------------------------------------------------------------- ctx[bh][d][e] = sum_t k*v
// k fp32, v bf16. One block = 128x128 output for a 256-long t-chunk; atomicAdd reduce.
__global__ __launch_bounds__(256) void ctx_kernel(
    const float* __restrict__ k, const unsigned short* __restrict__ vb,
    float* __restrict__ ctx)
{
  const int bh = blockIdx.x; const int b = bh >> 3, h = bh & 7;
  const int t0 = blockIdx.y * 256;
  const int tid  = threadIdx.x;
  const int lrow = tid >> 5;
  const int lcol = (tid & 31) << 2;
  const int tx   = tid & 15, ty = tid >> 4;
  __shared__ float Ks[16][132];
  __shared__ float Vs[16][132];
  float acc[8][8] = {};
  const size_t rbase = ((size_t)b*T_ + t0) * C_ + (size_t)h * D_;

  for (int kt = 0; kt < 256; kt += 16) {
    const size_t r0 = rbase + (size_t)(kt + lrow) * C_ + lcol;
    const size_t r1 = r0 + (size_t)8 * C_;
    float4 k0 = *(const float4*)&k[r0];
    float4 k1 = *(const float4*)&k[r1];
    ushort4 v0 = *(const ushort4*)&vb[r0];
    ushort4 v1 = *(const ushort4*)&vb[r1];
    __syncthreads();
    *(float4*)&Ks[lrow  ][lcol] = k0;
    *(float4*)&Ks[lrow+8][lcol] = k1;
    Vs[lrow][lcol+0] = b2f(v0.x); Vs[lrow][lcol+1] = b2f(v0.y);
    Vs[lrow][lcol+2] = b2f(v0.z); Vs[lrow][lcol+3] = b2f(v0.w);
    Vs[lrow+8][lcol+0] = b2f(v1.x); Vs[lrow+8][lcol+1] = b2f(v1.y);
    Vs[lrow+8][lcol+2] = b2f(v1.z); Vs[lrow+8][lcol+3] = b2f(v1.w);
    __syncthreads();
#pragma unroll
    for (int kk = 0; kk < 16; ++kk) {
      float a[8], bb[8];
      *(float4*)&a[0]  = *(const float4*)&Ks[kk][ty*8];
      *(float4*)&a[4]  = *(const float4*)&Ks[kk][ty*8+4];
      *(float4*)&bb[0] = *(const float4*)&Vs[kk][tx*8];
      *(float4*)&bb[4] = *(const float4*)&Vs[kk][tx*8+4];
#pragma unroll
      for (int i = 0; i < 8; ++i)
#pragma unroll
        for (int j = 0; j < 8; ++j)
          acc[i][j] = fmaf(a[i], bb[j], acc[i][j]);
    }
  }
  float* cb = ctx + (size_t)bh * (D_*D_);
#pragma unroll
  for (int i = 0; i < 8; ++i)
#pragma unroll
    for (int j = 0; j < 8; ++j)
      atomicAdd(&cb[(size_t)(ty*8+i)*D_ + tx*8 + j], acc[i][j]);
}

// ---------------------------------------------------------------- y = (q @ ctx)*Dinv + q -> bf16
__global__ __launch_bounds__(256) void y_gemm(
    const float* __restrict__ q, const float* __restrict__ ctx,
    const float* __restrict__ dinv, unsigned short* __restrict__ yb)
{
  const int bh = blockIdx.y; const int b = bh >> 3, h = bh & 7;
  const int t0 = blockIdx.x * 128;
  const int tid  = threadIdx.x;
  const int arow = tid >> 2, acol = (tid & 3) << 2;
  const int brow = tid >> 5, bcol = (tid & 31) << 2;
  const int tx   = tid & 15, ty = tid >> 4;
  __shared__ float As[16][132];
  __shared__ float Bs[16][132];
  float acc[8][8] = {};
  const size_t qbase = ((size_t)b*T_ + t0) * C_ + (size_t)h * D_;
  const float* cbase = ctx + (size_t)bh * (D_*D_);

  for (int k0 = 0; k0 < 128; k0 += 16) {
    float4 a0 = *(const float4*)&q[qbase + (size_t)arow      * C_ + k0 + acol];
    float4 a1 = *(const float4*)&q[qbase + (size_t)(arow+64) * C_ + k0 + acol];
    float4 b0 = *(const float4*)&cbase[(size_t)(k0+brow  )*D_ + bcol];
    float4 b1 = *(const float4*)&cbase[(size_t)(k0+brow+8)*D_ + bcol];
    __syncthreads();
    As[acol+0][arow]    = a0.x; As[acol+1][arow]    = a0.y;
    As[acol+2][arow]    = a0.z; As[acol+3][arow]    = a0.w;
    As[acol+0][arow+64] = a1.x; As[acol+1][arow+64] = a1.y;
    As[acol+2][arow+64] = a1.z; As[acol+3][arow+64] = a1.w;
    *(float4*)&Bs[brow  ][bcol] = b0;
    *(float4*)&Bs[brow+8][bcol] = b1;
    __syncthreads();
#pragma unroll
    for (int kk = 0; kk < 16; ++kk) {
      float a[8], bb[8];
      *(float4*)&a[0]  = *(const float4*)&As[kk][ty*8];
      *(float4*)&a[4]  = *(const float4*)&As[kk][ty*8+4];
      *(float4*)&bb[0] = *(const float4*)&Bs[kk][tx*8];
      *(float4*)&bb[4] = *(const float4*)&Bs[kk][tx*8+4];
#pragma unroll
      for (int i = 0; i < 8; ++i)
#pragma unroll
        for (int j = 0; j < 8; ++j)
          acc[i][j] = fmaf(a[i], bb[j], acc[i][j]);
    }
  }

  const float* dv = dinv + (size_t)bh * T_ + t0;
#pragma unroll
  for (int i = 0; i < 8; ++i) {
    const int t = ty*8 + i;
    const float di = dv[t];
    const size_t ro = qbase + (size_t)t * C_ + tx*8;
    float4 q0 = *(const float4*)&q[ro];
    float4 q1 = *(const float4*)&q[ro+4];
    union { unsigned short s[8]; uint4 v; } pk;
    pk.s[0] = f2b(fmaf(acc[i][0], di, q0.x)); pk.s[1] = f2b(fmaf(acc[i][1], di, q0.y));
    pk.s[2] = f2b(fmaf(acc[i][2], di, q0.z)); pk.s[3] = f2b(fmaf(acc[i][3], di, q0.w));
    pk.s[4] = f2b(fmaf(acc[i][4], di, q1.x)); pk.s[5] = f2b(fmaf(acc[i][5], di, q1.y));
    pk.s[6] = f2b(fmaf(acc[i][6], di, q1.z)); pk.s[7] = f2b(fmaf(acc[i][7], di, q1.w));
    *(uint4*)&yb[ro] = pk.v;
  }
}

// ---------------------------------------------------------------- launch
extern "C" void kernel_launch(void* const* d_in, const int* in_sizes, int n_in,
                              void* d_out, int out_size, void* d_ws, size_t ws_size,
                              hipStream_t stream)
{
  const float* x  = (const float*)d_in[0];
  const float* Wq = (const float*)d_in[1];
  const float* bq = (const float*)d_in[2];
  const float* Wk = (const float*)d_in[3];
  const float* bk = (const float*)d_in[4];
  const float* Wv = (const float*)d_in[5];
  const float* bv = (const float*)d_in[6];
  const float* Wp = (const float*)d_in[7];
  const float* bp = (const float*)d_in[8];
  float* out = (float*)d_out;

  // workspace layout (bytes):
  //   xb  bf16 [M][C]      @   0   (64 MiB)   -- reused as yb after v-GEMM
  //   q   fp32 [M][C]      @  64   (128 MiB)
  //   k   fp32 [M][C]      @ 192   (128 MiB)
  //   vb  bf16 [M][C]      @ 320   (64 MiB)
  //   Wt  bf16 4x[N][K]    @ 384   (8 MiB)
  //   ctx fp32 [32][128^2] @ 392   (2 MiB)
  //   ksum fp32            @ 394   (16 KiB)
  //   dinv fp32            @ 395   (1 MiB)     total ~396 MiB
  char* w = (char*)d_ws;
  unsigned short* xb = (unsigned short*)w;
  float* q  = (float*)(w + (64UL  << 20));
  float* k  = (float*)(w + (192UL << 20));
  unsigned short* vb = (unsigned short*)(w + (320UL << 20));
  unsigned short* Wtq = (unsigned short*)(w + (384UL << 20));
  unsigned short* Wtk = Wtq + 1024*1024;
  unsigned short* Wtv = Wtk + 1024*1024;
  unsigned short* Wtp = Wtv + 1024*1024;
  float* ctx  = (float*)(w + (392UL << 20));
  float* ksum = (float*)(w + (394UL << 20));
  float* dinv = (float*)(w + (395UL << 20));
  unsigned short* yb = xb;   // xb dead after v-GEMM

  hipMemsetAsync(ctx, 0, (2UL << 20) + 16384, stream);   // ctx + ksum (contiguous)

  dim3 blk(256);
  dim3 gconvT(32, 32);
  dim3 ggemm(C_/128, M_/128);   // 8 x 256

  conv_bf16<<<dim3(M_*C_/2048), blk, 0, stream>>>(x, xb);
  convT_w<<<gconvT, blk, 0, stream>>>(Wq, Wtq);
  convT_w<<<gconvT, blk, 0, stream>>>(Wk, Wtk);
  convT_w<<<gconvT, blk, 0, stream>>>(Wv, Wtv);
  convT_w<<<gconvT, blk, 0, stream>>>(Wp, Wtp);

  mfma_gemm_bias<float>         <<<ggemm, blk, 0, stream>>>(xb, Wtq, bq, q,  M_, C_, C_);
  mfma_gemm_bias<float>         <<<ggemm, blk, 0, stream>>>(xb, Wtk, bk, k,  M_, C_, C_);
  mfma_gemm_bias<unsigned short><<<ggemm, blk, 0, stream>>>(xb, Wtv, bv, vb, M_, C_, C_);

  softmax_head<<<dim3(M_*H_/4), blk, 0, stream>>>(k, nullptr, nullptr);
  ksum_kernel <<<dim3(B_*H_, 16), blk, 0, stream>>>(k, ksum);
  softmax_head<<<dim3(M_*H_/4), blk, 0, stream>>>(q, ksum, dinv);
  ctx_kernel  <<<dim3(B_*H_, 32), blk, 0, stream>>>(k, vb, ctx);
  y_gemm      <<<dim3(T_/128, B_*H_), blk, 0, stream>>>(q, ctx, dinv, yb);

  mfma_gemm_bias<float><<<ggemm, blk, 0, stream>>>(yb, Wtp, bp, out, M_, C_, C_);
}